// Round 13
// baseline (213.894 us; speedup 1.0000x reference)
//
#include <hip/hip_runtime.h>
#include <hip/hip_bf16.h>

#define N_NODES 50000
#define N_EDGES 800000
#define BSHIFT  5
#define BUCKS   1563           // ceil(50000 / 32)
#define NPAD    50016          // BUCKS * 32
#define BSTRIDE 1024           // slots per bucket (mean 512, ~22 sigma headroom)
#define BCAP    1024
#define IN_DIM  100
#define HID     128
#define BN_EPS  1e-5f
#define NSLICE  32             // stats atomic slices

#define SC_BLKS 98             // scatter blocks: ceil(800000/8192)
#define XB_BLKS 782            // x-cast blocks: ceil(NPAD*16/1024)
#define WT_BLKS 64             // weight-cast blocks: 4*16384/1024

typedef unsigned int uint;
typedef unsigned short u16;
typedef unsigned char u8;
typedef __attribute__((ext_vector_type(8))) unsigned short us8;
typedef __attribute__((ext_vector_type(8))) short s8;       // bf16 MFMA frag
typedef __attribute__((ext_vector_type(16))) float f16v;    // 32x32 accumulator
typedef __attribute__((ext_vector_type(4))) float f4;
typedef __attribute__((ext_vector_type(2))) float f2;
typedef __attribute__((ext_vector_type(2))) uint uv2;

__device__ __forceinline__ u16 f2bf(float f) {
    uint u = __builtin_bit_cast(uint, f);
    uint r = (u + 0x7FFFu + ((u >> 16) & 1u)) >> 16;   // RNE
    return (u16)r;
}
__device__ __forceinline__ uint pack2(float a, float b) {
    return (uint)f2bf(a) | ((uint)f2bf(b) << 16);
}
__device__ __forceinline__ float bfu(u16 v) { return __builtin_bit_cast(float, (uint)v << 16); }

template <typename T>
__device__ __forceinline__ T ntload(const T* p) {
    return __builtin_nontemporal_load(const_cast<T*>(p));
}
template <typename T>
__device__ __forceinline__ void ntstore(T* p, T v) {
    __builtin_nontemporal_store(v, p);
}

// ---------------------------------------------------------------------------
// Preprocessing: blocks [0,98) scatter edges into buckets; [98,880) cast x
// -> bf16 xb (root/MFMA) AND fp8 xq (gather payload, 128 B/row);
// [880,944) cast weights transposed.
// ---------------------------------------------------------------------------
__global__ __launch_bounds__(1024) void scatter_cast(
    const int* __restrict__ src, const int* __restrict__ dst,
    int* __restrict__ bcursor, uint* __restrict__ ebuf,
    const float* __restrict__ x,
    const float* __restrict__ W_l0, const float* __restrict__ W_r0,
    const float* __restrict__ W_l1, const float* __restrict__ W_r1,
    u16* __restrict__ xb, u8* __restrict__ xq, u16* __restrict__ Wt) {
    int t = threadIdx.x;
    int bid = blockIdx.x;

    if (bid >= SC_BLKS + XB_BLKS) {
        // ---- weights cast (scalar, small)
        int i2 = (bid - SC_BLKS - XB_BLKS) * 1024 + t;
        int w = i2 >> 14, i3 = i2 & 16383;
        const float* s = (w == 0) ? W_l0 : (w == 1) ? W_r0 : (w == 2) ? W_l1 : W_r1;
        int Ks = (w < 2) ? IN_DIM : HID;
        int n = i3 >> 7, k = i3 & 127;
        float v = (k < Ks) ? s[k * 128 + n] : 0.f;
        Wt[i2] = f2bf(v);
        return;
    }
    if (bid >= SC_BLKS) {
        // ---- x cast: 8 cols per thread -> us8 bf16 + uv2 fp8
        int g = (bid - SC_BLKS) * 1024 + t;
        if (g < NPAD * 16) {
            int row = g >> 4, k0 = (g & 15) * 8;
            float fv[8];
            #pragma unroll
            for (int j = 0; j < 8; ++j) fv[j] = 0.f;
            if (row < N_NODES && k0 < IN_DIM) {
                if (k0 + 8 <= IN_DIM) {
                    f4 a = *(const f4*)(x + row * IN_DIM + k0);
                    f4 b4 = *(const f4*)(x + row * IN_DIM + k0 + 4);
                    fv[0] = a.x; fv[1] = a.y; fv[2] = a.z; fv[3] = a.w;
                    fv[4] = b4.x; fv[5] = b4.y; fv[6] = b4.z; fv[7] = b4.w;
                } else {
                    #pragma unroll
                    for (int j = 0; j < 8; ++j)
                        fv[j] = (k0 + j < IN_DIM) ? x[row * IN_DIM + k0 + j] : 0.f;
                }
            }
            us8 o;
            #pragma unroll
            for (int j = 0; j < 8; ++j) o[j] = f2bf(fv[j]);
            *((us8*)xb + g) = o;
            int lo = __builtin_amdgcn_cvt_pk_fp8_f32(fv[0], fv[1], 0, false);
            lo = __builtin_amdgcn_cvt_pk_fp8_f32(fv[2], fv[3], lo, true);
            int hi = __builtin_amdgcn_cvt_pk_fp8_f32(fv[4], fv[5], 0, false);
            hi = __builtin_amdgcn_cvt_pk_fp8_f32(fv[6], fv[7], hi, true);
            uv2 q; q[0] = (uint)lo; q[1] = (uint)hi;
            *((uv2*)xq + g) = q;
        }
        return;
    }

    // ---- scatter phase: 8192 edges per block
    __shared__ int h[BUCKS];
    __shared__ int gb[BUCKS];
    for (int i = t; i < BUCKS; i += 1024) h[i] = 0;
    __syncthreads();
    int base = bid * 8192;
    int myb[8]; uint myv[8];
    #pragma unroll
    for (int r = 0; r < 8; ++r) {
        int e = base + r * 1024 + t;
        int b = -1; uint val = 0;
        if (e < N_EDGES) {
            int d = dst[e];
            b = d >> BSHIFT;
            val = (uint)src[e] | ((uint)(d & 31) << 16);
            atomicAdd(&h[b], 1);
        }
        myb[r] = b; myv[r] = val;
    }
    __syncthreads();
    for (int i = t; i < BUCKS; i += 1024) {
        int c = h[i];
        gb[i] = c ? (i * BSTRIDE + atomicAdd(&bcursor[i], c)) : 0;
        h[i] = 0;
    }
    __syncthreads();
    #pragma unroll
    for (int r = 0; r < 8; ++r) {
        int b = myb[r];
        if (b >= 0) {
            int pos = gb[b] + atomicAdd(&h[b], 1);
            ebuf[pos] = myv[r];
        }
    }
}

// ---------------------------------------------------------------------------
// Fused per-bucket kernel (R8: fp8 gather 128B/row = one cache line per
// edge). LDS CSR -> quad-owns-node gather-mean with HW fp8->f32 cvt
// (BN+ReLU in-reg if APPLY_BN) -> 32x32x16 MFMA (root-A bf16) -> nt store
// (+ fp8 copy for next layer's gather) + fp32 BN stats.
// ---------------------------------------------------------------------------
template <int APPLY_BN, int WRITE_BF16>
__global__ __launch_bounds__(256) void agg_gemm(
    const uint* __restrict__ ebuf, const int* __restrict__ bcursor,
    const u16* __restrict__ X,          // bf16 rows (root path)
    const u8* __restrict__ Xq,          // fp8 rows (gather path)
    const u16* __restrict__ WtL, const u16* __restrict__ WtR,
    const float* __restrict__ bias,
    float* __restrict__ outf, u16* __restrict__ outb, u8* __restrict__ outq,
    float* __restrict__ gstats_out,
    const float* __restrict__ gstats_in,
    const float* __restrict__ gamma, const float* __restrict__ beta,
    float inv_n) {
    __shared__ u16 Aagg[32][136];        // 8704 B
    __shared__ uint eL[BCAP];            // 4096 B
    __shared__ u16 srcL[BCAP];           // 2048 B
    __shared__ int cnt[32], ro[33], cur[32];
    __shared__ float s1L[128], s2L[128];
    __shared__ float ss[256];            // BN scale/shift (APPLY_BN)

    int b = blockIdx.x;
    int t = threadIdx.x;
    int row0 = b * 32;
    int wave = t >> 6, lane = t & 63;
    int quad = lane >> 4, sub = lane & 15;

    // ---- preamble: BN scale/shift from layer-0 stats (L2-hot, 32 KB)
    if (APPLY_BN && t < 128) {
        float m = 0.f, q = 0.f;
        #pragma unroll
        for (int s = 0; s < NSLICE; ++s) {
            m += gstats_in[s * 256 + t];
            q += gstats_in[s * 256 + 128 + t];
        }
        float mean = m * inv_n;
        float var = q * inv_n - mean * mean;
        float inv = 1.0f / sqrtf(var + BN_EPS);
        float sc = gamma[t] * inv;
        ss[t] = sc;
        ss[128 + t] = beta[t] - mean * sc;
    }

    // ---- bucket-local CSR in LDS
    int n = bcursor[b];
    if (n > BCAP) n = BCAP;
    if (t < 32) cnt[t] = 0;
    if (t < 128) { s1L[t] = 0.f; s2L[t] = 0.f; }
    __syncthreads();
    for (int i = t; i < n; i += 256) {
        uint p = ntload(ebuf + b * BSTRIDE + i);
        eL[i] = p;
        atomicAdd(&cnt[p >> 16], 1);
    }
    __syncthreads();
    if (t < 32) {
        int v = cnt[t];
        int s = v;
        #pragma unroll
        for (int off = 1; off < 32; off <<= 1) {
            int u = __shfl_up(s, off, 64);
            if (t >= off) s += u;
        }
        ro[t] = s - v;
        cur[t] = s - v;
        if (t == 31) ro[32] = s;
    }
    __syncthreads();
    for (int i = t; i < n; i += 256) {
        uint p = eL[i];
        int pos = atomicAdd(&cur[p >> 16], 1);
        srcL[pos] = (u16)(p & 0xFFFFu);
    }
    __syncthreads();

    // ---- gather-mean: each of 16 quads owns 2 nodes; fp8 rows, 8 B/lane
    float scr[8], shr[8];
    if (APPLY_BN) {
        #pragma unroll
        for (int j = 0; j < 8; ++j) {
            scr[j] = ss[sub * 8 + j];
            shr[j] = ss[128 + sub * 8 + j];
        }
    }
    int nl0 = (wave * 4 + quad) * 2;
    uint boff = (uint)sub * 8u;
    #pragma unroll
    for (int g = 0; g < 2; ++g) {
        int nl = nl0 + g;
        int rb = ro[nl], re = ro[nl + 1];
        float a[8];
        #pragma unroll
        for (int j = 0; j < 8; ++j) a[j] = 0.f;

        auto acc1 = [&](uv2 v) {
            f2 p0 = __builtin_amdgcn_cvt_pk_f32_fp8((int)v[0], false);
            f2 p1 = __builtin_amdgcn_cvt_pk_f32_fp8((int)v[0], true);
            f2 p2 = __builtin_amdgcn_cvt_pk_f32_fp8((int)v[1], false);
            f2 p3 = __builtin_amdgcn_cvt_pk_f32_fp8((int)v[1], true);
            float f[8] = { p0[0], p0[1], p1[0], p1[1], p2[0], p2[1], p3[0], p3[1] };
            #pragma unroll
            for (int j = 0; j < 8; ++j) {
                float val = f[j];
                if (APPLY_BN) val = fmaxf(fmaf(val, scr[j], shr[j]), 0.f);
                a[j] += val;
            }
        };

        int e = rb;
        for (; e + 4 <= re; e += 4) {
            int s0 = srcL[e], s1 = srcL[e + 1], s2 = srcL[e + 2], s3 = srcL[e + 3];
            uv2 v0 = *(const uv2*)(Xq + (size_t)s0 * 128 + boff);
            uv2 v1 = *(const uv2*)(Xq + (size_t)s1 * 128 + boff);
            uv2 v2 = *(const uv2*)(Xq + (size_t)s2 * 128 + boff);
            uv2 v3 = *(const uv2*)(Xq + (size_t)s3 * 128 + boff);
            acc1(v0); acc1(v1); acc1(v2); acc1(v3);
        }
        for (; e < re; ++e) {
            uv2 v0 = *(const uv2*)(Xq + (size_t)srcL[e] * 128 + boff);
            acc1(v0);
        }
        float inv = 1.0f / fmaxf((float)(re - rb), 1.0f);
        uint4 o;
        o.x = pack2(a[0] * inv, a[1] * inv);
        o.y = pack2(a[2] * inv, a[3] * inv);
        o.z = pack2(a[4] * inv, a[5] * inv);
        o.w = pack2(a[6] * inv, a[7] * inv);
        *(uint4*)&Aagg[nl][sub * 8] = o;
    }
    __syncthreads();   // Aagg complete

    // ---- dual GEMM: wave -> rows 0..31 of tile, cols cn..cn+31
    int m31 = lane & 31;
    int kh  = lane >> 5;
    int cn = wave * 32;
    f16v acc = (f16v)0.f;

    {
        s8 a_nxt = *(const s8*)&Aagg[m31][kh * 8];
        s8 b_nxt = *(const s8*)(WtL + (cn + m31) * 128 + kh * 8);
        #pragma unroll
        for (int ks = 0; ks < 8; ++ks) {
            s8 a_cur = a_nxt, b_cur = b_nxt;
            if (ks < 7) {
                a_nxt = *(const s8*)&Aagg[m31][(ks + 1) * 16 + kh * 8];
                b_nxt = *(const s8*)(WtL + (cn + m31) * 128 + (ks + 1) * 16 + kh * 8);
            }
            acc = __builtin_amdgcn_mfma_f32_32x32x16_bf16(a_cur, b_cur, acc, 0, 0, 0);
        }
    }
    {
        const u16* xrow = X + (size_t)(row0 + m31) * 128;
        us8 a_nxt = *(const us8*)(xrow + kh * 8);
        s8 b_nxt = *(const s8*)(WtR + (cn + m31) * 128 + kh * 8);
        #pragma unroll
        for (int ks = 0; ks < 8; ++ks) {
            us8 a_raw = a_nxt;
            s8 b_cur = b_nxt;
            if (ks < 7) {
                a_nxt = *(const us8*)(xrow + (ks + 1) * 16 + kh * 8);
                b_nxt = *(const s8*)(WtR + (cn + m31) * 128 + (ks + 1) * 16 + kh * 8);
            }
            s8 a_cur;
            if (APPLY_BN) {
                int kb = ks * 16 + kh * 8;
                #pragma unroll
                for (int j = 0; j < 8; ++j) {
                    float f = bfu(a_raw[j]);
                    f = fmaxf(fmaf(f, ss[kb + j], ss[128 + kb + j]), 0.f);
                    a_cur[j] = (short)f2bf(f);
                }
            } else {
                a_cur = __builtin_bit_cast(s8, a_raw);
            }
            acc = __builtin_amdgcn_mfma_f32_32x32x16_bf16(a_cur, b_cur, acc, 0, 0, 0);
        }
    }

    // ---- epilogue: nt store (+ fp8 copy) + BN partial stats
    // C/D 32x32: col=lane&31, row=(reg&3)+8*(reg>>2)+4*(lane>>5)  [m74/m101]
    {
        int col = cn + m31;
        float bv = bias[col];
        float s1 = 0.f, s2 = 0.f;
        #pragma unroll
        for (int reg = 0; reg < 16; ++reg) {
            int rowin = (reg & 3) + 8 * (reg >> 2) + 4 * kh;
            int row = row0 + rowin;
            if (row < N_NODES) {
                float v = acc[reg] + bv;
                if (WRITE_BF16) {
                    ntstore(outb + (size_t)row * 128 + col, f2bf(v));
                    int w8 = __builtin_amdgcn_cvt_pk_fp8_f32(v, v, 0, false);
                    outq[(size_t)row * 128 + col] = (u8)(w8 & 0xFF);
                } else {
                    ntstore(outf + (size_t)row * 128 + col, v);
                }
                s1 += v;
                s2 = fmaf(v, v, s2);
            }
        }
        s1 += __shfl_xor(s1, 32, 64);
        s2 += __shfl_xor(s2, 32, 64);
        if (lane < 32) {
            atomicAdd(&s1L[col], s1);
            atomicAdd(&s2L[col], s2);
        }
    }
    __syncthreads();
    int slice = b & (NSLICE - 1);
    if (t < 128) {
        atomicAdd(&gstats_out[slice * 256 + t], s1L[t]);
        atomicAdd(&gstats_out[slice * 256 + 128 + t], s2L[t]);
    }
}

// ---------------------------------------------------------------------------
// final BN, fp32 in-place on d_out
// ---------------------------------------------------------------------------
__global__ void bn_apply_kernel(float* __restrict__ h,
                                const float* __restrict__ gstats,
                                const float* __restrict__ gamma,
                                const float* __restrict__ beta,
                                float inv_n, int total4) {
    __shared__ float ss[256];
    int t = threadIdx.x;
    if (t < 128) {
        float m = 0.f, q = 0.f;
        #pragma unroll
        for (int s = 0; s < NSLICE; ++s) {
            m += gstats[s * 256 + t];
            q += gstats[s * 256 + 128 + t];
        }
        float mean = m * inv_n;
        float var = q * inv_n - mean * mean;
        float inv = 1.0f / sqrtf(var + BN_EPS);
        float sc = gamma[t] * inv;
        ss[t] = sc;
        ss[128 + t] = beta[t] - mean * sc;
    }
    __syncthreads();
    for (int i = blockIdx.x * 256 + t; i < total4; i += gridDim.x * 256) {
        int cg = i & 31;
        float4 v = ((float4*)h)[i];
        float4 sc = *(const float4*)&ss[cg * 4];
        float4 sh = *(const float4*)&ss[128 + cg * 4];
        v.x = fmaf(v.x, sc.x, sh.x);
        v.y = fmaf(v.y, sc.y, sh.y);
        v.z = fmaf(v.z, sc.z, sh.z);
        v.w = fmaf(v.w, sc.w, sh.w);
        ((float4*)h)[i] = v;
    }
}

// ---------------------------------------------------------------------------
extern "C" void kernel_launch(void* const* d_in, const int* in_sizes, int n_in,
                              void* d_out, int out_size, void* d_ws, size_t ws_size,
                              hipStream_t stream) {
    const float* x      = (const float*)d_in[0];
    const int*   ei     = (const int*)d_in[1];
    const float* W_l0   = (const float*)d_in[2];
    const float* b_l0   = (const float*)d_in[3];
    const float* W_r0   = (const float*)d_in[4];
    const float* gamma0 = (const float*)d_in[5];
    const float* beta0  = (const float*)d_in[6];
    const float* W_l1   = (const float*)d_in[7];
    const float* b_l1   = (const float*)d_in[8];
    const float* W_r1   = (const float*)d_in[9];
    const float* gamma1 = (const float*)d_in[10];
    const float* beta1  = (const float*)d_in[11];

    const int* src = ei;
    const int* dst = ei + N_EDGES;

    char* w = (char*)d_ws;
    auto alloc = [&](size_t bytes) {
        void* p = (void*)w;
        w += (bytes + 255) & ~(size_t)255;
        return p;
    };
    char* zbase    = w;
    float* gstats0 = (float*)alloc(sizeof(float) * NSLICE * 256);
    float* gstats1 = (float*)alloc(sizeof(float) * NSLICE * 256);
    int* bcursor   = (int*)alloc(sizeof(int) * BUCKS);
    size_t zbytes  = (size_t)(w - zbase);

    uint* ebuf     = (uint*)alloc(sizeof(uint) * (size_t)BUCKS * BSTRIDE);
    u16* xb        = (u16*)alloc(sizeof(u16) * (size_t)NPAD * 128);
    u16* hb        = (u16*)alloc(sizeof(u16) * (size_t)NPAD * 128);
    u8* xq         = (u8*)alloc(sizeof(u8) * (size_t)NPAD * 128);
    u8* hq         = (u8*)alloc(sizeof(u8) * (size_t)NPAD * 128);
    u16* Wt        = (u16*)alloc(sizeof(u16) * 4 * 16384);
    float* outp    = (float*)d_out;

    hipMemsetAsync(zbase, 0, zbytes, stream);

    const float inv_n = 1.0f / (float)N_NODES;
    const int total4 = N_NODES * HID / 4;

    // preprocessing: scatter + vectorized dual casts, one launch
    scatter_cast<<<SC_BLKS + XB_BLKS + WT_BLKS, 1024, 0, stream>>>(
        src, dst, bcursor, ebuf, x, W_l0, W_r0, W_l1, W_r1, xb, xq, Wt);

    // Layer 0: fused agg+gemm+stats, h -> bf16 hb + fp8 hq
    agg_gemm<0, 1><<<BUCKS, 256, 0, stream>>>(
        ebuf, bcursor, xb, xq, Wt, Wt + 16384, b_l0,
        nullptr, hb, hq, gstats0, nullptr, nullptr, nullptr, inv_n);

    // Layer 1: fused agg+gemm+stats, fp8 gather of h with BN+ReLU -> fp32 out
    agg_gemm<1, 0><<<BUCKS, 256, 0, stream>>>(
        ebuf, bcursor, hb, hq, Wt + 2 * 16384, Wt + 3 * 16384, b_l1,
        outp, nullptr, nullptr, gstats1, gstats0, gamma0, beta0, inv_n);

    bn_apply_kernel<<<2048, 256, 0, stream>>>(outp, gstats1, gamma1, beta1, inv_n, total4);
}

// Round 14
// 209.383 us; speedup vs baseline: 1.0215x; 1.0215x over previous
//
#include <hip/hip_runtime.h>
#include <hip/hip_bf16.h>

#define N_NODES 50000
#define N_EDGES 800000
#define BSHIFT  5
#define BUCKS   1563           // ceil(50000 / 32)
#define NPAD    50016          // BUCKS * 32
#define BSTRIDE 1024           // slots per bucket (mean 512, ~22 sigma headroom)
#define BCAP    1024
#define IN_DIM  100
#define HID     128
#define BN_EPS  1e-5f
#define NSLICE  32             // stats atomic slices

#define SC_BLKS 98             // scatter blocks: ceil(800000/8192)
#define XB_BLKS 782            // x-cast blocks: ceil(NPAD*16/1024)
#define WT_BLKS 64             // weight-cast blocks: 4*16384/1024

typedef unsigned int uint;
typedef unsigned short u16;
typedef unsigned char u8;
typedef __attribute__((ext_vector_type(8))) unsigned short us8;
typedef __attribute__((ext_vector_type(8))) short s8;       // bf16 MFMA frag
typedef __attribute__((ext_vector_type(16))) float f16v;    // 32x32 accumulator
typedef __attribute__((ext_vector_type(4))) float f4;
typedef __attribute__((ext_vector_type(2))) float f2;
typedef __attribute__((ext_vector_type(2))) uint uv2;

__device__ __forceinline__ u16 f2bf(float f) {
    uint u = __builtin_bit_cast(uint, f);
    uint r = (u + 0x7FFFu + ((u >> 16) & 1u)) >> 16;   // RNE
    return (u16)r;
}
__device__ __forceinline__ uint pack2(float a, float b) {
    return (uint)f2bf(a) | ((uint)f2bf(b) << 16);
}
__device__ __forceinline__ float bfu(u16 v) { return __builtin_bit_cast(float, (uint)v << 16); }

template <typename T>
__device__ __forceinline__ T ntload(const T* p) {
    return __builtin_nontemporal_load(const_cast<T*>(p));
}
template <typename T>
__device__ __forceinline__ void ntstore(T* p, T v) {
    __builtin_nontemporal_store(v, p);
}

// ---------------------------------------------------------------------------
// Preprocessing: blocks [0,98) scatter edges into buckets; [98,880) cast x
// -> bf16 xb (root/MFMA) AND fp8 xq (gather payload, 128 B/row);
// [880,944) cast weights transposed.  (unchanged from R13)
// ---------------------------------------------------------------------------
__global__ __launch_bounds__(1024) void scatter_cast(
    const int* __restrict__ src, const int* __restrict__ dst,
    int* __restrict__ bcursor, uint* __restrict__ ebuf,
    const float* __restrict__ x,
    const float* __restrict__ W_l0, const float* __restrict__ W_r0,
    const float* __restrict__ W_l1, const float* __restrict__ W_r1,
    u16* __restrict__ xb, u8* __restrict__ xq, u16* __restrict__ Wt) {
    int t = threadIdx.x;
    int bid = blockIdx.x;

    if (bid >= SC_BLKS + XB_BLKS) {
        // ---- weights cast (scalar, small)
        int i2 = (bid - SC_BLKS - XB_BLKS) * 1024 + t;
        int w = i2 >> 14, i3 = i2 & 16383;
        const float* s = (w == 0) ? W_l0 : (w == 1) ? W_r0 : (w == 2) ? W_l1 : W_r1;
        int Ks = (w < 2) ? IN_DIM : HID;
        int n = i3 >> 7, k = i3 & 127;
        float v = (k < Ks) ? s[k * 128 + n] : 0.f;
        Wt[i2] = f2bf(v);
        return;
    }
    if (bid >= SC_BLKS) {
        // ---- x cast: 8 cols per thread -> us8 bf16 + uv2 fp8
        int g = (bid - SC_BLKS) * 1024 + t;
        if (g < NPAD * 16) {
            int row = g >> 4, k0 = (g & 15) * 8;
            float fv[8];
            #pragma unroll
            for (int j = 0; j < 8; ++j) fv[j] = 0.f;
            if (row < N_NODES && k0 < IN_DIM) {
                if (k0 + 8 <= IN_DIM) {
                    f4 a = *(const f4*)(x + row * IN_DIM + k0);
                    f4 b4 = *(const f4*)(x + row * IN_DIM + k0 + 4);
                    fv[0] = a.x; fv[1] = a.y; fv[2] = a.z; fv[3] = a.w;
                    fv[4] = b4.x; fv[5] = b4.y; fv[6] = b4.z; fv[7] = b4.w;
                } else {
                    #pragma unroll
                    for (int j = 0; j < 8; ++j)
                        fv[j] = (k0 + j < IN_DIM) ? x[row * IN_DIM + k0 + j] : 0.f;
                }
            }
            us8 o;
            #pragma unroll
            for (int j = 0; j < 8; ++j) o[j] = f2bf(fv[j]);
            *((us8*)xb + g) = o;
            int lo = __builtin_amdgcn_cvt_pk_fp8_f32(fv[0], fv[1], 0, false);
            lo = __builtin_amdgcn_cvt_pk_fp8_f32(fv[2], fv[3], lo, true);
            int hi = __builtin_amdgcn_cvt_pk_fp8_f32(fv[4], fv[5], 0, false);
            hi = __builtin_amdgcn_cvt_pk_fp8_f32(fv[6], fv[7], hi, true);
            uv2 q; q[0] = (uint)lo; q[1] = (uint)hi;
            *((uv2*)xq + g) = q;
        }
        return;
    }

    // ---- scatter phase: 8192 edges per block
    __shared__ int h[BUCKS];
    __shared__ int gb[BUCKS];
    for (int i = t; i < BUCKS; i += 1024) h[i] = 0;
    __syncthreads();
    int base = bid * 8192;
    int myb[8]; uint myv[8];
    #pragma unroll
    for (int r = 0; r < 8; ++r) {
        int e = base + r * 1024 + t;
        int b = -1; uint val = 0;
        if (e < N_EDGES) {
            int d = dst[e];
            b = d >> BSHIFT;
            val = (uint)src[e] | ((uint)(d & 31) << 16);
            atomicAdd(&h[b], 1);
        }
        myb[r] = b; myv[r] = val;
    }
    __syncthreads();
    for (int i = t; i < BUCKS; i += 1024) {
        int c = h[i];
        gb[i] = c ? (i * BSTRIDE + atomicAdd(&bcursor[i], c)) : 0;
        h[i] = 0;
    }
    __syncthreads();
    #pragma unroll
    for (int r = 0; r < 8; ++r) {
        int b = myb[r];
        if (b >= 0) {
            int pos = gb[b] + atomicAdd(&h[b], 1);
            ebuf[pos] = myv[r];
        }
    }
}

// ---------------------------------------------------------------------------
// Fused per-bucket kernel: 512 threads, ONE node per quad (32 quads) —
// halves the per-quad serial gather chain vs R13. NO min-wave forcing in
// launch_bounds so the 4-deep load pipeline keeps its VGPR budget (R1's
// confound removed). Waves 0-3 do the dual GEMM + epilogue.
// ---------------------------------------------------------------------------
template <int APPLY_BN, int WRITE_BF16>
__global__ __launch_bounds__(512) void agg_gemm(
    const uint* __restrict__ ebuf, const int* __restrict__ bcursor,
    const u16* __restrict__ X,          // bf16 rows (root path)
    const u8* __restrict__ Xq,          // fp8 rows (gather path)
    const u16* __restrict__ WtL, const u16* __restrict__ WtR,
    const float* __restrict__ bias,
    float* __restrict__ outf, u16* __restrict__ outb, u8* __restrict__ outq,
    float* __restrict__ gstats_out,
    const float* __restrict__ gstats_in,
    const float* __restrict__ gamma, const float* __restrict__ beta,
    float inv_n) {
    __shared__ u16 Aagg[32][136];        // 8704 B
    __shared__ uint eL[BCAP];            // 4096 B
    __shared__ u16 srcL[BCAP];           // 2048 B
    __shared__ int cnt[32], ro[33], cur[32];
    __shared__ float s1L[128], s2L[128];
    __shared__ float ss[256];            // BN scale/shift (APPLY_BN)

    int b = blockIdx.x;
    int t = threadIdx.x;
    int row0 = b * 32;
    int wave = t >> 6, lane = t & 63;
    int quad = lane >> 4, sub = lane & 15;

    // ---- preamble: BN scale/shift from layer-0 stats (L2-hot, 32 KB)
    if (APPLY_BN && t < 128) {
        float m = 0.f, q = 0.f;
        #pragma unroll
        for (int s = 0; s < NSLICE; ++s) {
            m += gstats_in[s * 256 + t];
            q += gstats_in[s * 256 + 128 + t];
        }
        float mean = m * inv_n;
        float var = q * inv_n - mean * mean;
        float inv = 1.0f / sqrtf(var + BN_EPS);
        float sc = gamma[t] * inv;
        ss[t] = sc;
        ss[128 + t] = beta[t] - mean * sc;
    }

    // ---- bucket-local CSR in LDS (512-thread strides)
    int n = bcursor[b];
    if (n > BCAP) n = BCAP;
    if (t < 32) cnt[t] = 0;
    if (t < 128) { s1L[t] = 0.f; s2L[t] = 0.f; }
    __syncthreads();
    for (int i = t; i < n; i += 512) {
        uint p = ntload(ebuf + b * BSTRIDE + i);
        eL[i] = p;
        atomicAdd(&cnt[p >> 16], 1);
    }
    __syncthreads();
    if (t < 32) {
        int v = cnt[t];
        int s = v;
        #pragma unroll
        for (int off = 1; off < 32; off <<= 1) {
            int u = __shfl_up(s, off, 64);
            if (t >= off) s += u;
        }
        ro[t] = s - v;
        cur[t] = s - v;
        if (t == 31) ro[32] = s;
    }
    __syncthreads();
    for (int i = t; i < n; i += 512) {
        uint p = eL[i];
        int pos = atomicAdd(&cur[p >> 16], 1);
        srcL[pos] = (u16)(p & 0xFFFFu);
    }
    __syncthreads();

    // ---- gather-mean: each of 32 quads owns exactly 1 node; fp8, 8 B/lane
    float scr[8], shr[8];
    if (APPLY_BN) {
        #pragma unroll
        for (int j = 0; j < 8; ++j) {
            scr[j] = ss[sub * 8 + j];
            shr[j] = ss[128 + sub * 8 + j];
        }
    }
    {
        int nl = wave * 4 + quad;
        int rb = ro[nl], re = ro[nl + 1];
        uint boff = (uint)sub * 8u;
        float a[8];
        #pragma unroll
        for (int j = 0; j < 8; ++j) a[j] = 0.f;

        auto acc1 = [&](uv2 v) {
            f2 p0 = __builtin_amdgcn_cvt_pk_f32_fp8((int)v[0], false);
            f2 p1 = __builtin_amdgcn_cvt_pk_f32_fp8((int)v[0], true);
            f2 p2 = __builtin_amdgcn_cvt_pk_f32_fp8((int)v[1], false);
            f2 p3 = __builtin_amdgcn_cvt_pk_f32_fp8((int)v[1], true);
            float f[8] = { p0[0], p0[1], p1[0], p1[1], p2[0], p2[1], p3[0], p3[1] };
            #pragma unroll
            for (int j = 0; j < 8; ++j) {
                float val = f[j];
                if (APPLY_BN) val = fmaxf(fmaf(val, scr[j], shr[j]), 0.f);
                a[j] += val;
            }
        };

        int e = rb;
        for (; e + 4 <= re; e += 4) {
            int s0 = srcL[e], s1 = srcL[e + 1], s2 = srcL[e + 2], s3 = srcL[e + 3];
            uv2 v0 = *(const uv2*)(Xq + (size_t)s0 * 128 + boff);
            uv2 v1 = *(const uv2*)(Xq + (size_t)s1 * 128 + boff);
            uv2 v2 = *(const uv2*)(Xq + (size_t)s2 * 128 + boff);
            uv2 v3 = *(const uv2*)(Xq + (size_t)s3 * 128 + boff);
            acc1(v0); acc1(v1); acc1(v2); acc1(v3);
        }
        for (; e < re; ++e) {
            uv2 v0 = *(const uv2*)(Xq + (size_t)srcL[e] * 128 + boff);
            acc1(v0);
        }
        float inv = 1.0f / fmaxf((float)(re - rb), 1.0f);
        uint4 o;
        o.x = pack2(a[0] * inv, a[1] * inv);
        o.y = pack2(a[2] * inv, a[3] * inv);
        o.z = pack2(a[4] * inv, a[5] * inv);
        o.w = pack2(a[6] * inv, a[7] * inv);
        *(uint4*)&Aagg[nl][sub * 8] = o;
    }
    __syncthreads();   // Aagg complete

    // ---- dual GEMM on waves 0-3: wave -> rows 0..31, cols cn..cn+31
    if (wave < 4) {
        int m31 = lane & 31;
        int kh  = lane >> 5;
        int cn = wave * 32;
        f16v acc = (f16v)0.f;

        {
            s8 a_nxt = *(const s8*)&Aagg[m31][kh * 8];
            s8 b_nxt = *(const s8*)(WtL + (cn + m31) * 128 + kh * 8);
            #pragma unroll
            for (int ks = 0; ks < 8; ++ks) {
                s8 a_cur = a_nxt, b_cur = b_nxt;
                if (ks < 7) {
                    a_nxt = *(const s8*)&Aagg[m31][(ks + 1) * 16 + kh * 8];
                    b_nxt = *(const s8*)(WtL + (cn + m31) * 128 + (ks + 1) * 16 + kh * 8);
                }
                acc = __builtin_amdgcn_mfma_f32_32x32x16_bf16(a_cur, b_cur, acc, 0, 0, 0);
            }
        }
        {
            const u16* xrow = X + (size_t)(row0 + m31) * 128;
            us8 a_nxt = *(const us8*)(xrow + kh * 8);
            s8 b_nxt = *(const s8*)(WtR + (cn + m31) * 128 + kh * 8);
            #pragma unroll
            for (int ks = 0; ks < 8; ++ks) {
                us8 a_raw = a_nxt;
                s8 b_cur = b_nxt;
                if (ks < 7) {
                    a_nxt = *(const us8*)(xrow + (ks + 1) * 16 + kh * 8);
                    b_nxt = *(const s8*)(WtR + (cn + m31) * 128 + (ks + 1) * 16 + kh * 8);
                }
                s8 a_cur;
                if (APPLY_BN) {
                    int kb = ks * 16 + kh * 8;
                    #pragma unroll
                    for (int j = 0; j < 8; ++j) {
                        float f = bfu(a_raw[j]);
                        f = fmaxf(fmaf(f, ss[kb + j], ss[128 + kb + j]), 0.f);
                        a_cur[j] = (short)f2bf(f);
                    }
                } else {
                    a_cur = __builtin_bit_cast(s8, a_raw);
                }
                acc = __builtin_amdgcn_mfma_f32_32x32x16_bf16(a_cur, b_cur, acc, 0, 0, 0);
            }
        }

        // ---- epilogue: nt store (+ fp8 copy) + BN partial stats
        // C/D 32x32: col=lane&31, row=(reg&3)+8*(reg>>2)+4*(lane>>5)
        {
            int col = cn + m31;
            float bv = bias[col];
            float s1 = 0.f, s2 = 0.f;
            #pragma unroll
            for (int reg = 0; reg < 16; ++reg) {
                int rowin = (reg & 3) + 8 * (reg >> 2) + 4 * kh;
                int row = row0 + rowin;
                if (row < N_NODES) {
                    float v = acc[reg] + bv;
                    if (WRITE_BF16) {
                        ntstore(outb + (size_t)row * 128 + col, f2bf(v));
                        int w8 = __builtin_amdgcn_cvt_pk_fp8_f32(v, v, 0, false);
                        outq[(size_t)row * 128 + col] = (u8)(w8 & 0xFF);
                    } else {
                        ntstore(outf + (size_t)row * 128 + col, v);
                    }
                    s1 += v;
                    s2 = fmaf(v, v, s2);
                }
            }
            s1 += __shfl_xor(s1, 32, 64);
            s2 += __shfl_xor(s2, 32, 64);
            if (lane < 32) {
                atomicAdd(&s1L[col], s1);
                atomicAdd(&s2L[col], s2);
            }
        }
    }
    __syncthreads();
    int slice = b & (NSLICE - 1);
    if (t < 128) {
        atomicAdd(&gstats_out[slice * 256 + t], s1L[t]);
        atomicAdd(&gstats_out[slice * 256 + 128 + t], s2L[t]);
    }
}

// ---------------------------------------------------------------------------
// final BN, fp32 in-place on d_out
// ---------------------------------------------------------------------------
__global__ void bn_apply_kernel(float* __restrict__ h,
                                const float* __restrict__ gstats,
                                const float* __restrict__ gamma,
                                const float* __restrict__ beta,
                                float inv_n, int total4) {
    __shared__ float ss[256];
    int t = threadIdx.x;
    if (t < 128) {
        float m = 0.f, q = 0.f;
        #pragma unroll
        for (int s = 0; s < NSLICE; ++s) {
            m += gstats[s * 256 + t];
            q += gstats[s * 256 + 128 + t];
        }
        float mean = m * inv_n;
        float var = q * inv_n - mean * mean;
        float inv = 1.0f / sqrtf(var + BN_EPS);
        float sc = gamma[t] * inv;
        ss[t] = sc;
        ss[128 + t] = beta[t] - mean * sc;
    }
    __syncthreads();
    for (int i = blockIdx.x * 256 + t; i < total4; i += gridDim.x * 256) {
        int cg = i & 31;
        float4 v = ((float4*)h)[i];
        float4 sc = *(const float4*)&ss[cg * 4];
        float4 sh = *(const float4*)&ss[128 + cg * 4];
        v.x = fmaf(v.x, sc.x, sh.x);
        v.y = fmaf(v.y, sc.y, sh.y);
        v.z = fmaf(v.z, sc.z, sh.z);
        v.w = fmaf(v.w, sc.w, sh.w);
        ((float4*)h)[i] = v;
    }
}

// ---------------------------------------------------------------------------
extern "C" void kernel_launch(void* const* d_in, const int* in_sizes, int n_in,
                              void* d_out, int out_size, void* d_ws, size_t ws_size,
                              hipStream_t stream) {
    const float* x      = (const float*)d_in[0];
    const int*   ei     = (const int*)d_in[1];
    const float* W_l0   = (const float*)d_in[2];
    const float* b_l0   = (const float*)d_in[3];
    const float* W_r0   = (const float*)d_in[4];
    const float* gamma0 = (const float*)d_in[5];
    const float* beta0  = (const float*)d_in[6];
    const float* W_l1   = (const float*)d_in[7];
    const float* b_l1   = (const float*)d_in[8];
    const float* W_r1   = (const float*)d_in[9];
    const float* gamma1 = (const float*)d_in[10];
    const float* beta1  = (const float*)d_in[11];

    const int* src = ei;
    const int* dst = ei + N_EDGES;

    char* w = (char*)d_ws;
    auto alloc = [&](size_t bytes) {
        void* p = (void*)w;
        w += (bytes + 255) & ~(size_t)255;
        return p;
    };
    char* zbase    = w;
    float* gstats0 = (float*)alloc(sizeof(float) * NSLICE * 256);
    float* gstats1 = (float*)alloc(sizeof(float) * NSLICE * 256);
    int* bcursor   = (int*)alloc(sizeof(int) * BUCKS);
    size_t zbytes  = (size_t)(w - zbase);

    uint* ebuf     = (uint*)alloc(sizeof(uint) * (size_t)BUCKS * BSTRIDE);
    u16* xb        = (u16*)alloc(sizeof(u16) * (size_t)NPAD * 128);
    u16* hb        = (u16*)alloc(sizeof(u16) * (size_t)NPAD * 128);
    u8* xq         = (u8*)alloc(sizeof(u8) * (size_t)NPAD * 128);
    u8* hq         = (u8*)alloc(sizeof(u8) * (size_t)NPAD * 128);
    u16* Wt        = (u16*)alloc(sizeof(u16) * 4 * 16384);
    float* outp    = (float*)d_out;

    hipMemsetAsync(zbase, 0, zbytes, stream);

    const float inv_n = 1.0f / (float)N_NODES;
    const int total4 = N_NODES * HID / 4;

    // preprocessing: scatter + vectorized dual casts, one launch
    scatter_cast<<<SC_BLKS + XB_BLKS + WT_BLKS, 1024, 0, stream>>>(
        src, dst, bcursor, ebuf, x, W_l0, W_r0, W_l1, W_r1, xb, xq, Wt);

    // Layer 0: fused agg+gemm+stats, h -> bf16 hb + fp8 hq
    agg_gemm<0, 1><<<BUCKS, 512, 0, stream>>>(
        ebuf, bcursor, xb, xq, Wt, Wt + 16384, b_l0,
        nullptr, hb, hq, gstats0, nullptr, nullptr, nullptr, inv_n);

    // Layer 1: fused agg+gemm+stats, fp8 gather of h with BN+ReLU -> fp32 out
    agg_gemm<1, 0><<<BUCKS, 512, 0, stream>>>(
        ebuf, bcursor, hb, hq, Wt + 2 * 16384, Wt + 3 * 16384, b_l1,
        outp, nullptr, nullptr, gstats1, gstats0, gamma0, beta0, inv_n);

    bn_apply_kernel<<<2048, 256, 0, stream>>>(outp, gstats1, gamma1, beta1, inv_n, total4);
}